// Round 1
// baseline (1801.179 us; speedup 1.0000x reference)
//
#include <hip/hip_runtime.h>

#define DMv 384
#define DEv 64
#define NBG 41
#define NEB 8

// ---------- bf16 helpers (raw ushort storage) ----------
__device__ __forceinline__ float bf_lo(unsigned u){ return __uint_as_float(u << 16); }
__device__ __forceinline__ float bf_hi(unsigned u){ return __uint_as_float(u & 0xffff0000u); }
__device__ __forceinline__ unsigned short f2bf(float f){
  unsigned u = __float_as_uint(f);
  unsigned r = (u + 0x7fffu + ((u >> 16) & 1u)) >> 16;
  return (unsigned short)r;
}
__device__ __forceinline__ float bf2f(unsigned short s){ return __uint_as_float(((unsigned)s) << 16); }

// ---------- atom embedding: h = lut[x] * sqrt(384) ----------
__global__ void embed_k(const int* __restrict__ x, const float* __restrict__ lut,
                        float* __restrict__ h) {
  int n = blockIdx.x, c = threadIdx.x;
  h[(size_t)n*DMv + c] = lut[(size_t)x[n]*DMv + c] * 19.595917942265423f;
}

// ---------- gaussian basis + edge embedding: ea = basis @ We0 + be0 (bf16 out) ----------
__global__ void ea_gauss_k(const float* __restrict__ edge_attr,
                           const float* __restrict__ We0, const float* __restrict__ be0,
                           unsigned short* __restrict__ ea, int Ecnt) {
  __shared__ float bas[4][48];
  int tid = threadIdx.x, lane = tid & 63, wv = tid >> 6;
  int e = blockIdx.x*4 + wv;
  if (e >= Ecnt) return;
  float d = edge_attr[e];
  if (lane < NBG) {
    float diff = (d - 0.2f*(float)lane) * 5.0f;
    bas[wv][lane] = __expf(-(diff*diff)) * (1.0f/1.12f);
  }
  asm volatile("s_waitcnt lgkmcnt(0)" ::: "memory");
  float sum = be0[lane];
  #pragma unroll
  for (int k = 0; k < NBG; ++k)
    sum = fmaf(bas[wv][k], We0[k*DEv + lane], sum);
  ea[(size_t)e*DEv + lane] = f2bf(sum);
}

// ---------- CSR build ----------
__global__ void count_k(const int* __restrict__ tgt, int* __restrict__ cnt, int Ecnt) {
  int e = blockIdx.x*256 + threadIdx.x;
  if (e < Ecnt) atomicAdd(&cnt[tgt[e]], 1);
}
__global__ void scan1_k(const int* __restrict__ cnt, int* __restrict__ rowptr,
                        int* __restrict__ bsum, int n) {
  __shared__ int tmp[256];
  int tid = threadIdx.x, i = blockIdx.x*256 + tid;
  int v = (i < n) ? cnt[i] : 0;
  tmp[tid] = v; __syncthreads();
  for (int off = 1; off < 256; off <<= 1) {
    int xv = (tid >= off) ? tmp[tid-off] : 0;
    __syncthreads();
    tmp[tid] += xv;
    __syncthreads();
  }
  if (i < n) rowptr[i] = tmp[tid] - v;
  if (tid == 255) bsum[blockIdx.x] = tmp[255];
}
__global__ void scan2_k(const int* __restrict__ bsum, int* __restrict__ bsumx, int nb) {
  __shared__ int tmp[256];
  int tid = threadIdx.x;
  int v = (tid < nb) ? bsum[tid] : 0;
  tmp[tid] = v; __syncthreads();
  for (int off = 1; off < 256; off <<= 1) {
    int xv = (tid >= off) ? tmp[tid-off] : 0;
    __syncthreads();
    tmp[tid] += xv;
    __syncthreads();
  }
  bsumx[tid] = tmp[tid] - v;
}
__global__ void scan3_k(int* __restrict__ rowptr, const int* __restrict__ bsumx,
                        int n, int total) {
  int i = blockIdx.x*256 + threadIdx.x;
  if (i < n) rowptr[i] += bsumx[blockIdx.x];
  if (i == 0) rowptr[n] = total;
}
__global__ void fill_k(const int* __restrict__ tgt, const int* __restrict__ rowptr,
                       int* __restrict__ fill, int* __restrict__ eidx, int Ecnt) {
  int e = blockIdx.x*256 + threadIdx.x;
  if (e >= Ecnt) return;
  int t = tgt[e];
  int pos = rowptr[t] + atomicAdd(&fill[t], 1);
  eidx[pos] = e;
}

// ---------- self-loop attr: scatter-mean of ea over targets (via CSR) ----------
__global__ void loopattr_k(const unsigned short* __restrict__ eaE,
                           unsigned short* __restrict__ eaLoop,
                           const int* __restrict__ rowptr, const int* __restrict__ eidx,
                           int Nn) {
  int tid = threadIdx.x, lane = tid & 63, wv = tid >> 6;
  int t = blockIdx.x*4 + wv;
  if (t >= Nn) return;
  int rp = rowptr[t], deg = rowptr[t+1] - rp;
  float s = 0.f;
  for (int i = 0; i < deg; ++i) {
    int eid = eidx[rp + i];
    s += bf2f(eaE[(size_t)eid*DEv + lane]);
  }
  float m = (deg > 0) ? s / (float)deg : 0.f;
  eaLoop[(size_t)t*DEv + lane] = f2bf(m);
}

// ---------- fp32 SGEMM: C{0,1,2} = A @ B{0,1,2} + bias{0,1,2}  (K=N=384) ----------
__global__ __launch_bounds__(256) void sgemm3_k(
    const float* __restrict__ A,
    const float* __restrict__ B0, const float* __restrict__ B1, const float* __restrict__ B2,
    const float* __restrict__ bias0, const float* __restrict__ bias1, const float* __restrict__ bias2,
    float* __restrict__ C0, float* __restrict__ C1, float* __restrict__ C2, int M) {
  const int K = DMv, Ncol = DMv;
  int z = blockIdx.z;
  const float* B    = (z == 0) ? B0 : (z == 1) ? B1 : B2;
  const float* bias = (z == 0) ? bias0 : (z == 1) ? bias1 : bias2;
  float* C          = (z == 0) ? C0 : (z == 1) ? C1 : C2;
  __shared__ float As[16][68];
  __shared__ float Bs[16][68];
  int tid = threadIdx.x;
  int tx = tid & 15, ty = tid >> 4;
  int bm = blockIdx.y * 64, bn = blockIdx.x * 64;
  float acc[4][4] = {};
  int am  = tid >> 2;
  int ak4 = (tid & 3) * 4;
  int bk  = tid >> 4;
  int bn4 = (tid & 15) * 4;
  for (int k0 = 0; k0 < K; k0 += 16) {
    float4 av = make_float4(0.f, 0.f, 0.f, 0.f);
    if (bm + am < M) av = *(const float4*)(A + (size_t)(bm+am)*K + k0 + ak4);
    As[ak4+0][am] = av.x; As[ak4+1][am] = av.y; As[ak4+2][am] = av.z; As[ak4+3][am] = av.w;
    float4 bv = *(const float4*)(B + (size_t)(k0+bk)*Ncol + bn + bn4);
    *(float4*)&Bs[bk][bn4] = bv;
    __syncthreads();
    #pragma unroll
    for (int k = 0; k < 16; ++k) {
      float4 a = *(const float4*)&As[k][ty*4];
      float4 b = *(const float4*)&Bs[k][tx*4];
      acc[0][0] = fmaf(a.x, b.x, acc[0][0]); acc[0][1] = fmaf(a.x, b.y, acc[0][1]);
      acc[0][2] = fmaf(a.x, b.z, acc[0][2]); acc[0][3] = fmaf(a.x, b.w, acc[0][3]);
      acc[1][0] = fmaf(a.y, b.x, acc[1][0]); acc[1][1] = fmaf(a.y, b.y, acc[1][1]);
      acc[1][2] = fmaf(a.y, b.z, acc[1][2]); acc[1][3] = fmaf(a.y, b.w, acc[1][3]);
      acc[2][0] = fmaf(a.z, b.x, acc[2][0]); acc[2][1] = fmaf(a.z, b.y, acc[2][1]);
      acc[2][2] = fmaf(a.z, b.z, acc[2][2]); acc[2][3] = fmaf(a.z, b.w, acc[2][3]);
      acc[3][0] = fmaf(a.w, b.x, acc[3][0]); acc[3][1] = fmaf(a.w, b.y, acc[3][1]);
      acc[3][2] = fmaf(a.w, b.z, acc[3][2]); acc[3][3] = fmaf(a.w, b.w, acc[3][3]);
    }
    __syncthreads();
  }
  #pragma unroll
  for (int i = 0; i < 4; ++i) {
    int m = bm + ty*4 + i;
    if (m < M) {
      #pragma unroll
      for (int j = 0; j < 4; ++j) {
        int n = bn + tx*4 + j;
        C[(size_t)m*Ncol + n] = acc[i][j] + bias[n];
      }
    }
  }
}

// ---------- fused GAT layer: eproj + leaky + alpha + online softmax + aggregate
// ---------- + residual + LayerNorm.  One wave per target node, 2 nodes per wave. ----------
__global__ __launch_bounds__(256, 2) void fused_gat_k(
    const float* __restrict__ xl, const float* __restrict__ xr,
    const float* __restrict__ hres,
    const unsigned short* __restrict__ ea,           // [(E+N)][64] bf16
    const int* __restrict__ rowptr, const int* __restrict__ eidx,
    const int* __restrict__ srcs,
    const float* __restrict__ We_l,                  // [64][384] f32
    const float* __restrict__ att_l,                 // [384] f32
    const float* __restrict__ ln_g, const float* __restrict__ ln_b,
    float* __restrict__ h, int Nn, int Ecnt) {
  __shared__ unsigned short WeT[DMv * 68];           // [j][k], k-pad 68, bf16
  __shared__ float eas[4][NEB][DEv];
  int tid = threadIdx.x;
  // stage We (transposed, bf16) once per block
  for (int idx = tid; idx < DEv*DMv; idx += 256) {
    int k = idx / DMv, j = idx - k*DMv;
    WeT[j*68 + k] = f2bf(We_l[idx]);
  }
  __syncthreads();
  int lane = tid & 63, wv = tid >> 6;
  int j0 = lane * 6;
  for (int rep = 0; rep < 2; ++rep) {
    int t = blockIdx.x*8 + rep*4 + wv;
    if (t >= Nn) continue;
    int rp = rowptr[t], deg = rowptr[t+1] - rp;
    int items = deg + 1;                              // + self loop
    float att_j[6], xr_t[6];
    #pragma unroll
    for (int jj = 0; jj < 6; ++jj) {
      att_j[jj] = att_l[j0 + jj];
      xr_t[jj]  = xr[(size_t)t*DMv + j0 + jj];
    }
    float Mh = -INFINITY, S = 0.f;
    float acc[6] = {0.f,0.f,0.f,0.f,0.f,0.f};
    for (int base = 0; base < items; base += NEB) {
      int nb = items - base; if (nb > NEB) nb = NEB;
      // lanes 0..7 resolve slot (rid, src)
      int rid_v = Ecnt + t, src_v = t;
      if (lane < NEB) {
        int item = base + lane;
        if (item < deg) {
          int eid = eidx[rp + item];
          rid_v = eid; src_v = srcs[eid];
        }
      }
      // stage ea rows (bf16 -> f32 in LDS); slot s = lane>>3, 8 elems per lane
      int s_my = lane >> 3, sub = lane & 7;
      int rid_me = __shfl(rid_v, s_my);
      uint4 u = *(const uint4*)(ea + (size_t)rid_me*DEv + sub*8);
      float* dstp = &eas[wv][s_my][sub*8];
      dstp[0] = bf_lo(u.x); dstp[1] = bf_hi(u.x);
      dstp[2] = bf_lo(u.y); dstp[3] = bf_hi(u.y);
      dstp[4] = bf_lo(u.z); dstp[5] = bf_hi(u.z);
      dstp[6] = bf_lo(u.w); dstp[7] = bf_hi(u.w);
      // broadcast srcs, prefetch xl gathers (hidden under FMA loop)
      int sA[NEB];
      #pragma unroll
      for (int s = 0; s < NEB; ++s) sA[s] = __shfl(src_v, s);
      float xls[NEB][6];
      #pragma unroll
      for (int s = 0; s < NEB; ++s) {
        const float* xp = xl + (size_t)sA[s]*DMv + j0;
        #pragma unroll
        for (int jj = 0; jj < 6; ++jj) xls[s][jj] = xp[jj];
      }
      // wave-local fence: ea staging writes visible before reads below
      asm volatile("s_waitcnt lgkmcnt(0)" ::: "memory");
      // eproj = ea @ We for the batch
      float mm[NEB][6] = {};
      #pragma unroll 4
      for (int g = 0; g < 16; ++g) {
        float w[6][4];
        #pragma unroll
        for (int jj = 0; jj < 6; ++jj) {
          uint2 p = *(const uint2*)(WeT + (j0+jj)*68 + 4*g);
          w[jj][0] = bf_lo(p.x); w[jj][1] = bf_hi(p.x);
          w[jj][2] = bf_lo(p.y); w[jj][3] = bf_hi(p.y);
        }
        #pragma unroll
        for (int s = 0; s < NEB; ++s) {
          float4 ev = *(const float4*)&eas[wv][s][g*4];
          #pragma unroll
          for (int jj = 0; jj < 6; ++jj) {
            mm[s][jj] = fmaf(ev.x, w[jj][0], mm[s][jj]);
            mm[s][jj] = fmaf(ev.y, w[jj][1], mm[s][jj]);
            mm[s][jj] = fmaf(ev.z, w[jj][2], mm[s][jj]);
            mm[s][jj] = fmaf(ev.w, w[jj][3], mm[s][jj]);
          }
        }
      }
      // per-edge: alpha + online softmax update (head = lane group of 8)
      #pragma unroll
      for (int s = 0; s < NEB; ++s) {
        if (s < nb) {
          float part = 0.f;
          #pragma unroll
          for (int jj = 0; jj < 6; ++jj) {
            float v  = mm[s][jj] + xls[s][jj] + xr_t[jj];
            float vl = (v > 0.f) ? v : 0.2f*v;
            part = fmaf(vl, att_j[jj], part);
          }
          part += __shfl_xor(part, 1);
          part += __shfl_xor(part, 2);
          part += __shfl_xor(part, 4);
          if (part > Mh) {
            float f = __expf(Mh - part);
            S = fmaf(S, f, 1.0f);
            #pragma unroll
            for (int jj = 0; jj < 6; ++jj) acc[jj] = fmaf(acc[jj], f, xls[s][jj]);
            Mh = part;
          } else {
            float wgt = __expf(part - Mh);
            S += wgt;
            #pragma unroll
            for (int jj = 0; jj < 6; ++jj) acc[jj] = fmaf(wgt, xls[s][jj], acc[jj]);
          }
        }
      }
    }
    // finalize: normalize, residual, LayerNorm
    float inv = 1.0f / (S + 1e-16f);
    const float* hrp = hres + (size_t)t*DMv + j0;
    float outv[6]; float s1 = 0.f, s2 = 0.f;
    #pragma unroll
    for (int jj = 0; jj < 6; ++jj) {
      float o = fmaf(acc[jj], inv, hrp[jj]);
      outv[jj] = o; s1 += o; s2 += o*o;
    }
    #pragma unroll
    for (int m = 1; m < 64; m <<= 1) {
      s1 += __shfl_xor(s1, m);
      s2 += __shfl_xor(s2, m);
    }
    float mu  = s1 * (1.0f/384.0f);
    float var = s2 * (1.0f/384.0f) - mu*mu;
    float rs  = rsqrtf(var + 1e-5f);
    float* hp = h + (size_t)t*DMv + j0;
    #pragma unroll
    for (int jj = 0; jj < 6; ++jj)
      hp[jj] = (outv[jj] - mu)*rs*ln_g[j0+jj] + ln_b[j0+jj];
  }
}

// ---------- BatchNorm (training-mode batch stats) ----------
__global__ void bn_reduce_k(const float* __restrict__ h, float* __restrict__ sums, int Nn) {
  int c = threadIdx.x;
  float s = 0.f, s2 = 0.f;
  for (int r = blockIdx.x; r < Nn; r += gridDim.x) {
    float v = h[(size_t)r*DMv + c];
    s += v; s2 += v*v;
  }
  atomicAdd(&sums[c], s);
  atomicAdd(&sums[DMv + c], s2);
}
__global__ void bn_params_k(const float* __restrict__ sums,
                            const float* __restrict__ bn_g, const float* __restrict__ bn_b,
                            float* __restrict__ scsh, int Nn) {
  int c = threadIdx.x;
  float mu  = sums[c] / (float)Nn;
  float var = sums[DMv + c] / (float)Nn - mu*mu;
  float rs  = rsqrtf(var + 1e-5f);
  float sc  = bn_g[c] * rs;
  scsh[c] = sc;
  scsh[DMv + c] = bn_b[c] - mu*sc;
}
__global__ void bn_apply_k(const float* __restrict__ h, const float* __restrict__ scsh,
                           float* __restrict__ out) {
  int c = threadIdx.x; int n = blockIdx.x;
  size_t i = (size_t)n*DMv + c;
  out[i] = fmaf(h[i], scsh[c], scsh[DMv + c]);
}

extern "C" void kernel_launch(void* const* d_in, const int* in_sizes, int n_in,
                              void* d_out, int out_size, void* d_ws, size_t ws_size,
                              hipStream_t stream) {
  const int Nn   = in_sizes[0];
  const int Ecnt = in_sizes[2];
  const int*   x         = (const int*)d_in[0];
  const int*   eindex    = (const int*)d_in[1];
  const int*   srcs      = eindex;
  const int*   tgts      = eindex + Ecnt;
  const float* edge_attr = (const float*)d_in[2];
  const float* lut       = (const float*)d_in[3];
  const float* We0       = (const float*)d_in[4];
  const float* be0       = (const float*)d_in[5];
  const float* Wl        = (const float*)d_in[6];
  const float* bl_       = (const float*)d_in[7];
  const float* Wr        = (const float*)d_in[8];
  const float* br_       = (const float*)d_in[9];
  const float* We        = (const float*)d_in[10];
  const float* att       = (const float*)d_in[11];
  const float* Wres      = (const float*)d_in[12];
  const float* bias_g    = (const float*)d_in[13];
  const float* ln_g      = (const float*)d_in[14];
  const float* ln_b      = (const float*)d_in[15];
  const float* bn_g      = (const float*)d_in[16];
  const float* bn_b      = (const float*)d_in[17];

  char* ws = (char*)d_ws;
  size_t off = 0;
  auto alloc = [&](size_t b) { size_t o = off; off += (b + 255) & ~(size_t)255; return o; };
  float* h     = (float*)(ws + alloc((size_t)Nn*DMv*4));
  float* xlB   = (float*)(ws + alloc((size_t)Nn*DMv*4));
  float* xrB   = (float*)(ws + alloc((size_t)Nn*DMv*4));
  float* hresB = (float*)(ws + alloc((size_t)Nn*DMv*4));
  unsigned short* ea = (unsigned short*)(ws + alloc((size_t)(Ecnt+Nn)*DEv*2));
  int* rowptr  = (int*)(ws + alloc((size_t)(Nn+1)*4));
  int* cnt     = (int*)(ws + alloc((size_t)Nn*4));
  int* fillA   = (int*)(ws + alloc((size_t)Nn*4));
  int* eidxA   = (int*)(ws + alloc((size_t)Ecnt*4));
  int* bsum    = (int*)(ws + alloc(1024));
  int* bsumx   = (int*)(ws + alloc(1024));
  float* bnsum = (float*)(ws + alloc(2*DMv*4));
  float* scsh  = (float*)(ws + alloc(2*DMv*4));

  hipMemsetAsync(cnt,   0, (size_t)Nn*4, stream);
  hipMemsetAsync(fillA, 0, (size_t)Nn*4, stream);
  hipMemsetAsync(bnsum, 0, 2*DMv*4, stream);

  embed_k<<<Nn, DMv, 0, stream>>>(x, lut, h);
  ea_gauss_k<<<(Ecnt+3)/4, 256, 0, stream>>>(edge_attr, We0, be0, ea, Ecnt);
  count_k<<<(Ecnt+255)/256, 256, 0, stream>>>(tgts, cnt, Ecnt);
  int nblk = (Nn + 255)/256;
  scan1_k<<<nblk, 256, 0, stream>>>(cnt, rowptr, bsum, Nn);
  scan2_k<<<1, 256, 0, stream>>>(bsum, bsumx, nblk);
  scan3_k<<<nblk, 256, 0, stream>>>(rowptr, bsumx, Nn, Ecnt);
  fill_k<<<(Ecnt+255)/256, 256, 0, stream>>>(tgts, rowptr, fillA, eidxA, Ecnt);
  loopattr_k<<<(Nn+3)/4, 256, 0, stream>>>(ea, ea + (size_t)Ecnt*DEv, rowptr, eidxA, Nn);

  for (int l = 0; l < 2; ++l) {
    sgemm3_k<<<dim3(6, (Nn+63)/64, 3), 256, 0, stream>>>(
        h,
        Wl + (size_t)l*DMv*DMv, Wr + (size_t)l*DMv*DMv, Wres + (size_t)l*DMv*DMv,
        bl_ + (size_t)l*DMv, br_ + (size_t)l*DMv, bias_g + (size_t)l*DMv,
        xlB, xrB, hresB, Nn);
    fused_gat_k<<<(Nn+7)/8, 256, 0, stream>>>(
        xlB, xrB, hresB, ea, rowptr, eidxA, srcs,
        We + (size_t)l*DEv*DMv, att + (size_t)l*DMv,
        ln_g + (size_t)l*DMv, ln_b + (size_t)l*DMv,
        h, Nn, Ecnt);
  }
  bn_reduce_k<<<200, DMv, 0, stream>>>(h, bnsum, Nn);
  bn_params_k<<<1, DMv, 0, stream>>>(bnsum, bn_g, bn_b, scsh, Nn);
  bn_apply_k<<<Nn, DMv, 0, stream>>>(h, scsh, (float*)d_out);
}

// Round 2
// 1096.998 us; speedup vs baseline: 1.6419x; 1.6419x over previous
//
#include <hip/hip_runtime.h>

#define DMv 384
#define DEv 64
#define NEB 4

typedef __attribute__((ext_vector_type(8))) __bf16 bf16x8;
typedef __attribute__((ext_vector_type(4))) float f32x4;

// ---------- bf16 helpers (raw ushort storage) ----------
__device__ __forceinline__ float bf_lo(unsigned u){ return __uint_as_float(u << 16); }
__device__ __forceinline__ float bf_hi(unsigned u){ return __uint_as_float(u & 0xffff0000u); }
__device__ __forceinline__ unsigned short f2bf(float f){
  unsigned u = __float_as_uint(f);
  unsigned r = (u + 0x7fffu + ((u >> 16) & 1u)) >> 16;
  return (unsigned short)r;
}
__device__ __forceinline__ float bf2f(unsigned short s){ return __uint_as_float(((unsigned)s) << 16); }

// ---------- atom embedding: hbf = bf16(lut[x] * sqrt(384)) ----------
__global__ void embed_k(const int* __restrict__ x, const float* __restrict__ lut,
                        unsigned short* __restrict__ hbf) {
  int n = blockIdx.x, c = threadIdx.x;
  hbf[(size_t)n*DMv + c] = f2bf(lut[(size_t)x[n]*DMv + c] * 19.595917942265423f);
}

// ---------- W2 = We0 @ We  (f32 [2][44][384], rows 41..43 zero), bias2 = be0 @ We ----------
__global__ void w2_k(const float* __restrict__ We0, const float* __restrict__ be0,
                     const float* __restrict__ We, float* __restrict__ W2,
                     float* __restrict__ bias2) {
  int k = blockIdx.x;         // 0..44
  int l = blockIdx.y;
  int j = threadIdx.x;        // 0..383
  const float* Wel = We + (size_t)l*DEv*DMv;
  if (k == 44) {
    float s = 0.f;
    for (int c = 0; c < DEv; ++c) s = fmaf(be0[c], Wel[c*DMv + j], s);
    bias2[l*DMv + j] = s;
    return;
  }
  float s = 0.f;
  if (k < 41) {
    for (int c = 0; c < DEv; ++c) s = fmaf(We0[k*DEv + c], Wel[c*DMv + j], s);
  }
  W2[((size_t)l*44 + k)*DMv + j] = s;
}

// ---------- WcatT bf16 [2][1152][384]: rows = output col (Wl|Wr|Wres), contiguous K ----------
__global__ void wcat_k(const float* __restrict__ Wl, const float* __restrict__ Wr,
                       const float* __restrict__ Wres, unsigned short* __restrict__ WcatT) {
  int n = blockIdx.x;   // 0..1151
  int l = blockIdx.y;
  int k = threadIdx.x;  // 0..383
  const float* src;
  int nn;
  if (n < 384)      { src = Wl   + (size_t)l*DMv*DMv; nn = n; }
  else if (n < 768) { src = Wr   + (size_t)l*DMv*DMv; nn = n - 384; }
  else              { src = Wres + (size_t)l*DMv*DMv; nn = n - 768; }
  WcatT[((size_t)l*1152 + n)*DMv + k] = f2bf(src[(size_t)k*DMv + nn]);
}

// ---------- per-edge 8-value gaussian basis window (start mult of 4) ----------
__global__ void bas8_k(const float* __restrict__ edge_attr,
                       uint4* __restrict__ bas8, int* __restrict__ ofs, int Ecnt) {
  int e = blockIdx.x*256 + threadIdx.x;
  if (e >= Ecnt) return;
  float d = edge_attr[e];
  int kc = (int)(d*5.0f + 0.5f);
  int s = (kc - 2) & ~3;
  if (s < 0) s = 0;
  float v[8];
  #pragma unroll
  for (int i = 0; i < 8; ++i) {
    float df = (d - 0.2f*(float)(s+i)) * 5.0f;
    v[i] = __expf(-(df*df)) * (1.0f/1.12f);
  }
  uint4 u;
  u.x = (unsigned)f2bf(v[0]) | ((unsigned)f2bf(v[1]) << 16);
  u.y = (unsigned)f2bf(v[2]) | ((unsigned)f2bf(v[3]) << 16);
  u.z = (unsigned)f2bf(v[4]) | ((unsigned)f2bf(v[5]) << 16);
  u.w = (unsigned)f2bf(v[6]) | ((unsigned)f2bf(v[7]) << 16);
  bas8[e] = u;
  ofs[e] = s;
}

// ---------- CSR build ----------
__global__ void count_k(const int* __restrict__ tgt, int* __restrict__ cnt, int Ecnt) {
  int e = blockIdx.x*256 + threadIdx.x;
  if (e < Ecnt) atomicAdd(&cnt[tgt[e]], 1);
}
__global__ void scan1_k(const int* __restrict__ cnt, int* __restrict__ rowptr,
                        int* __restrict__ bsum, int n) {
  __shared__ int tmp[256];
  int tid = threadIdx.x, i = blockIdx.x*256 + tid;
  int v = (i < n) ? cnt[i] : 0;
  tmp[tid] = v; __syncthreads();
  for (int off = 1; off < 256; off <<= 1) {
    int xv = (tid >= off) ? tmp[tid-off] : 0;
    __syncthreads();
    tmp[tid] += xv;
    __syncthreads();
  }
  if (i < n) rowptr[i] = tmp[tid] - v;
  if (tid == 255) bsum[blockIdx.x] = tmp[255];
}
__global__ void scan2_k(const int* __restrict__ bsum, int* __restrict__ bsumx, int nb) {
  __shared__ int tmp[256];
  int tid = threadIdx.x;
  int v = (tid < nb) ? bsum[tid] : 0;
  tmp[tid] = v; __syncthreads();
  for (int off = 1; off < 256; off <<= 1) {
    int xv = (tid >= off) ? tmp[tid-off] : 0;
    __syncthreads();
    tmp[tid] += xv;
    __syncthreads();
  }
  bsumx[tid] = tmp[tid] - v;
}
__global__ void scan3_k(int* __restrict__ rowptr, const int* __restrict__ bsumx,
                        int n, int total) {
  int i = blockIdx.x*256 + threadIdx.x;
  if (i < n) rowptr[i] += bsumx[blockIdx.x];
  if (i == 0) rowptr[n] = total;
}
__global__ void fill_k(const int* __restrict__ tgt, const int* __restrict__ rowptr,
                       int* __restrict__ fill, int* __restrict__ eidx, int Ecnt) {
  int e = blockIdx.x*256 + threadIdx.x;
  if (e >= Ecnt) return;
  int t = tgt[e];
  int pos = rowptr[t] + atomicAdd(&fill[t], 1);
  eidx[pos] = e;
}

// ---------- self-loop e_proj: mean basis (dense 41) @ W2, both layers, bf16 out ----------
__global__ void loop_eproj_k(const float* __restrict__ edge_attr,
                             const int* __restrict__ rowptr, const int* __restrict__ eidx,
                             const float* __restrict__ W2,
                             unsigned short* __restrict__ eproj_loop, int Nn) {
  __shared__ float basw[4][41];
  int tid = threadIdx.x, lane = tid & 63, wv = tid >> 6;
  int t = blockIdx.x*4 + wv;
  if (t >= Nn) return;
  int rp = rowptr[t], deg = rowptr[t+1] - rp;
  float mb = 0.f;
  for (int base = 0; base < deg; base += 64) {
    int i = base + lane;
    float d_i = 0.f;
    if (i < deg) d_i = edge_attr[eidx[rp + i]];
    int nb = deg - base; if (nb > 64) nb = 64;
    for (int ii = 0; ii < nb; ++ii) {
      float d = __shfl(d_i, ii);
      if (lane < 41) {
        float df = (d - 0.2f*(float)lane) * 5.0f;
        mb += __expf(-(df*df));
      }
    }
  }
  if (lane < 41)
    basw[wv][lane] = (deg > 0) ? mb / ((float)deg * 1.12f) : 0.f;
  asm volatile("s_waitcnt lgkmcnt(0)" ::: "memory");
  int j0 = lane*6;
  for (int l = 0; l < 2; ++l) {
    float o[6] = {0.f,0.f,0.f,0.f,0.f,0.f};
    for (int k = 0; k < 41; ++k) {
      float b = basw[wv][k];
      const float* wp = W2 + ((size_t)l*44 + k)*DMv + j0;
      #pragma unroll
      for (int jj = 0; jj < 6; ++jj) o[jj] = fmaf(b, wp[jj], o[jj]);
    }
    unsigned short* op = eproj_loop + ((size_t)l*Nn + t)*DMv + j0;
    unsigned* op32 = (unsigned*)op;
    op32[0] = (unsigned)f2bf(o[0]) | ((unsigned)f2bf(o[1]) << 16);
    op32[1] = (unsigned)f2bf(o[2]) | ((unsigned)f2bf(o[3]) << 16);
    op32[2] = (unsigned)f2bf(o[4]) | ((unsigned)f2bf(o[5]) << 16);
  }
}

// ---------- bf16 MFMA GEMM: [M x 384] @ [384 x 1152] -> xl | xr | hres (f32, +bias) ----------
__global__ __launch_bounds__(256) void mfma_cat_k(
    const unsigned short* __restrict__ Abf,     // hbf [M][384]
    const unsigned short* __restrict__ Bt,      // WcatT layer [1152][384]
    const float* __restrict__ b0, const float* __restrict__ b1, const float* __restrict__ b2,
    float* __restrict__ C0, float* __restrict__ C1, float* __restrict__ C2, int M) {
  __shared__ unsigned short lds[2*8192];        // As 16KB | Bs 16KB, st_16x32 swizzled
  unsigned short* As = lds;
  unsigned short* Bs = lds + 8192;
  int tid = threadIdx.x;
  int lane = tid & 63, wv = tid >> 6;
  int wr = wv >> 1, wc = wv & 1;
  int bn = blockIdx.x * 128;
  int bm = blockIdx.y * 128;
  int srow = tid >> 3;            // 0..31
  int scol = (tid & 7) * 8;       // bf16 element col in [0,64)
  f32x4 acc[4][4] = {};
  uint4 av[4], bv[4];
  #pragma unroll
  for (int c = 0; c < 4; ++c) {
    int gr = bm + c*32 + srow; if (gr >= M) gr = M - 1;
    av[c] = *(const uint4*)(Abf + (size_t)gr*DMv + scol);
    bv[c] = *(const uint4*)(Bt + (size_t)(bn + c*32 + srow)*DMv + scol);
  }
  #pragma unroll
  for (int kt = 0; kt < 6; ++kt) {
    __syncthreads();
    #pragma unroll
    for (int c = 0; c < 4; ++c) {
      int r = c*32 + srow;
      int byteA = r*128 + scol*2;
      byteA ^= ((byteA >> 9) & 1) << 5;
      *(uint4*)((char*)As + byteA) = av[c];
      *(uint4*)((char*)Bs + byteA) = bv[c];
    }
    __syncthreads();
    if (kt < 5) {
      int k0 = (kt+1) * 64;
      #pragma unroll
      for (int c = 0; c < 4; ++c) {
        int gr = bm + c*32 + srow; if (gr >= M) gr = M - 1;
        av[c] = *(const uint4*)(Abf + (size_t)gr*DMv + k0 + scol);
        bv[c] = *(const uint4*)(Bt + (size_t)(bn + c*32 + srow)*DMv + k0 + scol);
      }
    }
    #pragma unroll
    for (int ks = 0; ks < 2; ++ks) {
      bf16x8 af[4], bfv[4];
      #pragma unroll
      for (int m = 0; m < 4; ++m) {
        int r = wr*64 + m*16 + (lane & 15);
        int byte = r*128 + ks*64 + ((lane >> 4)*16);
        byte ^= ((byte >> 9) & 1) << 5;
        af[m] = *(const bf16x8*)((const char*)As + byte);
      }
      #pragma unroll
      for (int n = 0; n < 4; ++n) {
        int r = wc*64 + n*16 + (lane & 15);
        int byte = r*128 + ks*64 + ((lane >> 4)*16);
        byte ^= ((byte >> 9) & 1) << 5;
        bfv[n] = *(const bf16x8*)((const char*)Bs + byte);
      }
      #pragma unroll
      for (int m = 0; m < 4; ++m)
        #pragma unroll
        for (int n = 0; n < 4; ++n)
          acc[m][n] = __builtin_amdgcn_mfma_f32_16x16x32_bf16(af[m], bfv[n], acc[m][n], 0, 0, 0);
    }
  }
  int seg = bn / 384;
  float* C = (seg == 0) ? C0 : (seg == 1) ? C1 : C2;
  const float* bias = (seg == 0) ? b0 : (seg == 1) ? b1 : b2;
  int cbase = bn - seg*384;
  #pragma unroll
  for (int n = 0; n < 4; ++n) {
    int col = cbase + wc*64 + n*16 + (lane & 15);
    float bsv = bias[col];
    #pragma unroll
    for (int m = 0; m < 4; ++m) {
      int r0 = bm + wr*64 + m*16 + ((lane >> 4)*4);
      #pragma unroll
      for (int q = 0; q < 4; ++q) {
        int r = r0 + q;
        if (r < M) C[(size_t)r*DMv + col] = acc[m][n][q] + bsv;
      }
    }
  }
}

// ---------- fused GAT layer v2: windowed basis @ W2 + online softmax + agg + LN ----------
__global__ __launch_bounds__(256, 4) void fused_gat2_k(
    const float* __restrict__ xl, const float* __restrict__ xr,
    const float* __restrict__ hres,
    const uint4* __restrict__ bas8, const int* __restrict__ ofs,
    const int* __restrict__ rowptr, const int* __restrict__ eidx,
    const int* __restrict__ srcs,
    const float* __restrict__ W2f,              // layer's [44][384] f32 (rows 41..43 zero)
    const float* __restrict__ bias2_l,          // [384]
    const unsigned short* __restrict__ eproj_loop_l,  // [N][384] bf16
    const float* __restrict__ att_l,
    const float* __restrict__ ln_g, const float* __restrict__ ln_b,
    unsigned short* __restrict__ hbf, int Nn) {
  __shared__ unsigned short W2T[DMv * 44];      // [j][k] col-major, 33.8 KB
  __shared__ float basS[4][NEB][8];
  __shared__ int ofsS[4][NEB];
  int tid = threadIdx.x;
  for (int i = tid; i < 44*DMv; i += 256) {
    int k = i / DMv, j = i - k*DMv;
    W2T[j*44 + k] = f2bf(W2f[i]);
  }
  __syncthreads();
  int lane = tid & 63, wv = tid >> 6;
  int j0 = lane * 6;
  for (int rep = 0; rep < 2; ++rep) {
    int t = blockIdx.x*8 + rep*4 + wv;
    if (t >= Nn) continue;
    int rp = rowptr[t], deg = rowptr[t+1] - rp;
    float att_j[6], xr_t[6];
    #pragma unroll
    for (int jj = 0; jj < 6; ++jj) {
      att_j[jj] = att_l[j0 + jj];
      xr_t[jj]  = xr[(size_t)t*DMv + j0 + jj] + bias2_l[j0 + jj];
    }
    float Mh = -INFINITY, S = 0.f;
    float acc[6] = {0.f,0.f,0.f,0.f,0.f,0.f};
    for (int base = 0; base < deg; base += NEB) {
      int nb = deg - base; if (nb > NEB) nb = NEB;
      int src_v = t;
      if (lane < NEB) {
        int item = base + lane;
        int idx = (item < deg) ? item : (deg - 1);
        int eid = eidx[rp + idx];
        src_v = srcs[eid];
        uint4 bu = bas8[eid];
        float* bp = &basS[wv][lane][0];
        *(float4*)bp     = make_float4(bf_lo(bu.x), bf_hi(bu.x), bf_lo(bu.y), bf_hi(bu.y));
        *(float4*)(bp+4) = make_float4(bf_lo(bu.z), bf_hi(bu.z), bf_lo(bu.w), bf_hi(bu.w));
        ofsS[wv][lane] = ofs[eid];
      }
      int sA[NEB];
      #pragma unroll
      for (int s = 0; s < NEB; ++s) sA[s] = __shfl(src_v, s);
      float xls[NEB][6];
      #pragma unroll
      for (int s = 0; s < NEB; ++s) {
        const float* xp = xl + (size_t)sA[s]*DMv + j0;
        float2 a = *(const float2*)xp;
        float2 b = *(const float2*)(xp+2);
        float2 c = *(const float2*)(xp+4);
        xls[s][0]=a.x; xls[s][1]=a.y; xls[s][2]=b.x; xls[s][3]=b.y; xls[s][4]=c.x; xls[s][5]=c.y;
      }
      asm volatile("s_waitcnt lgkmcnt(0)" ::: "memory");
      #pragma unroll
      for (int s = 0; s < NEB; ++s) {
        int s_e = ofsS[wv][s];
        float4 bb0 = *(const float4*)&basS[wv][s][0];
        float4 bb1 = *(const float4*)&basS[wv][s][4];
        float part = 0.f;
        #pragma unroll
        for (int jj = 0; jj < 6; ++jj) {
          const unsigned short* wp = W2T + (j0 + jj)*44 + s_e;
          uint2 wA = *(const uint2*)wp;
          uint2 wB = *(const uint2*)(wp + 4);
          float mv = xls[s][jj] + xr_t[jj];
          mv = fmaf(bb0.x, bf_lo(wA.x), mv);
          mv = fmaf(bb0.y, bf_hi(wA.x), mv);
          mv = fmaf(bb0.z, bf_lo(wA.y), mv);
          mv = fmaf(bb0.w, bf_hi(wA.y), mv);
          mv = fmaf(bb1.x, bf_lo(wB.x), mv);
          mv = fmaf(bb1.y, bf_hi(wB.x), mv);
          mv = fmaf(bb1.z, bf_lo(wB.y), mv);
          mv = fmaf(bb1.w, bf_hi(wB.y), mv);
          float vl = (mv > 0.f) ? mv : 0.2f*mv;
          part = fmaf(vl, att_j[jj], part);
        }
        part += __shfl_xor(part, 1);
        part += __shfl_xor(part, 2);
        part += __shfl_xor(part, 4);
        if (s < nb) {
          float nm = fmaxf(Mh, part);
          float f = __expf(Mh - nm);
          float w = __expf(part - nm);
          S = S*f + w;
          #pragma unroll
          for (int jj = 0; jj < 6; ++jj) acc[jj] = fmaf(acc[jj], f, w * xls[s][jj]);
          Mh = nm;
        }
      }
    }
    // self-loop
    {
      const float* xp = xl + (size_t)t*DMv + j0;
      float2 a = *(const float2*)xp;
      float2 b = *(const float2*)(xp+2);
      float2 c = *(const float2*)(xp+4);
      float xlt[6] = {a.x, a.y, b.x, b.y, c.x, c.y};
      const unsigned* ep = (const unsigned*)(eproj_loop_l + (size_t)t*DMv + j0);
      unsigned e0 = ep[0], e1 = ep[1], e2 = ep[2];
      float el[6] = {bf_lo(e0), bf_hi(e0), bf_lo(e1), bf_hi(e1), bf_lo(e2), bf_hi(e2)};
      float part = 0.f;
      #pragma unroll
      for (int jj = 0; jj < 6; ++jj) {
        float mv = el[jj] + xlt[jj] + xr_t[jj];
        float vl = (mv > 0.f) ? mv : 0.2f*mv;
        part = fmaf(vl, att_j[jj], part);
      }
      part += __shfl_xor(part, 1);
      part += __shfl_xor(part, 2);
      part += __shfl_xor(part, 4);
      float nm = fmaxf(Mh, part);
      float f = __expf(Mh - nm);
      float w = __expf(part - nm);
      S = S*f + w;
      #pragma unroll
      for (int jj = 0; jj < 6; ++jj) acc[jj] = fmaf(acc[jj], f, w * xlt[jj]);
      Mh = nm;
    }
    // finalize: normalize, residual, LayerNorm, write bf16
    float inv = 1.0f / (S + 1e-16f);
    const float* hrp = hres + (size_t)t*DMv + j0;
    float outv[6]; float s1 = 0.f, s2 = 0.f;
    #pragma unroll
    for (int jj = 0; jj < 6; ++jj) {
      float o = fmaf(acc[jj], inv, hrp[jj]);
      outv[jj] = o; s1 += o; s2 += o*o;
    }
    #pragma unroll
    for (int m = 1; m < 64; m <<= 1) {
      s1 += __shfl_xor(s1, m);
      s2 += __shfl_xor(s2, m);
    }
    float mu  = s1 * (1.0f/384.0f);
    float var = s2 * (1.0f/384.0f) - mu*mu;
    float rs  = rsqrtf(var + 1e-5f);
    float o0 = (outv[0]-mu)*rs*ln_g[j0+0] + ln_b[j0+0];
    float o1 = (outv[1]-mu)*rs*ln_g[j0+1] + ln_b[j0+1];
    float o2 = (outv[2]-mu)*rs*ln_g[j0+2] + ln_b[j0+2];
    float o3 = (outv[3]-mu)*rs*ln_g[j0+3] + ln_b[j0+3];
    float o4 = (outv[4]-mu)*rs*ln_g[j0+4] + ln_b[j0+4];
    float o5 = (outv[5]-mu)*rs*ln_g[j0+5] + ln_b[j0+5];
    unsigned* hp = (unsigned*)(hbf + (size_t)t*DMv + j0);
    hp[0] = (unsigned)f2bf(o0) | ((unsigned)f2bf(o1) << 16);
    hp[1] = (unsigned)f2bf(o2) | ((unsigned)f2bf(o3) << 16);
    hp[2] = (unsigned)f2bf(o4) | ((unsigned)f2bf(o5) << 16);
  }
}

// ---------- BatchNorm (training-mode batch stats) on bf16 h ----------
__global__ void bn_reduce_k(const unsigned short* __restrict__ hbf, float* __restrict__ sums, int Nn) {
  int c = threadIdx.x;
  float s = 0.f, s2 = 0.f;
  for (int r = blockIdx.x; r < Nn; r += gridDim.x) {
    float v = bf2f(hbf[(size_t)r*DMv + c]);
    s += v; s2 += v*v;
  }
  atomicAdd(&sums[c], s);
  atomicAdd(&sums[DMv + c], s2);
}
__global__ void bn_params_k(const float* __restrict__ sums,
                            const float* __restrict__ bn_g, const float* __restrict__ bn_b,
                            float* __restrict__ scsh, int Nn) {
  int c = threadIdx.x;
  float mu  = sums[c] / (float)Nn;
  float var = sums[DMv + c] / (float)Nn - mu*mu;
  float rs  = rsqrtf(var + 1e-5f);
  float sc  = bn_g[c] * rs;
  scsh[c] = sc;
  scsh[DMv + c] = bn_b[c] - mu*sc;
}
__global__ void bn_apply_k(const unsigned short* __restrict__ hbf, const float* __restrict__ scsh,
                           float* __restrict__ out) {
  int c = threadIdx.x; int n = blockIdx.x;
  size_t i = (size_t)n*DMv + c;
  out[i] = fmaf(bf2f(hbf[i]), scsh[c], scsh[DMv + c]);
}

extern "C" void kernel_launch(void* const* d_in, const int* in_sizes, int n_in,
                              void* d_out, int out_size, void* d_ws, size_t ws_size,
                              hipStream_t stream) {
  const int Nn   = in_sizes[0];
  const int Ecnt = in_sizes[2];
  const int*   x         = (const int*)d_in[0];
  const int*   eindex    = (const int*)d_in[1];
  const int*   srcs      = eindex;
  const int*   tgts      = eindex + Ecnt;
  const float* edge_attr = (const float*)d_in[2];
  const float* lut       = (const float*)d_in[3];
  const float* We0       = (const float*)d_in[4];
  const float* be0       = (const float*)d_in[5];
  const float* Wl        = (const float*)d_in[6];
  const float* bl_       = (const float*)d_in[7];
  const float* Wr        = (const float*)d_in[8];
  const float* br_       = (const float*)d_in[9];
  const float* We        = (const float*)d_in[10];
  const float* att       = (const float*)d_in[11];
  const float* Wres      = (const float*)d_in[12];
  const float* bias_g    = (const float*)d_in[13];
  const float* ln_g      = (const float*)d_in[14];
  const float* ln_b      = (const float*)d_in[15];
  const float* bn_g      = (const float*)d_in[16];
  const float* bn_b      = (const float*)d_in[17];

  char* ws = (char*)d_ws;
  size_t off = 0;
  auto alloc = [&](size_t b) { size_t o = off; off += (b + 255) & ~(size_t)255; return o; };
  unsigned short* hbf   = (unsigned short*)(ws + alloc((size_t)Nn*DMv*2));
  float* xlB   = (float*)(ws + alloc((size_t)Nn*DMv*4));
  float* xrB   = (float*)(ws + alloc((size_t)Nn*DMv*4));
  float* hresB = (float*)(ws + alloc((size_t)Nn*DMv*4));
  unsigned short* eproj_loop = (unsigned short*)(ws + alloc((size_t)2*Nn*DMv*2));
  uint4* bas8  = (uint4*)(ws + alloc((size_t)Ecnt*16));
  int* ofs     = (int*)(ws + alloc((size_t)Ecnt*4));
  float* W2    = (float*)(ws + alloc((size_t)2*44*DMv*4));
  float* bias2 = (float*)(ws + alloc((size_t)2*DMv*4));
  unsigned short* WcatT = (unsigned short*)(ws + alloc((size_t)2*1152*DMv*2));
  int* rowptr  = (int*)(ws + alloc((size_t)(Nn+1)*4));
  int* cnt     = (int*)(ws + alloc((size_t)Nn*4));
  int* fillA   = (int*)(ws + alloc((size_t)Nn*4));
  int* eidxA   = (int*)(ws + alloc((size_t)Ecnt*4));
  int* bsum    = (int*)(ws + alloc(1024));
  int* bsumx   = (int*)(ws + alloc(1024));
  float* bnsum = (float*)(ws + alloc(2*DMv*4));
  float* scsh  = (float*)(ws + alloc(2*DMv*4));

  hipMemsetAsync(cnt,   0, (size_t)Nn*4, stream);
  hipMemsetAsync(fillA, 0, (size_t)Nn*4, stream);
  hipMemsetAsync(bnsum, 0, 2*DMv*4, stream);

  embed_k<<<Nn, DMv, 0, stream>>>(x, lut, hbf);
  w2_k<<<dim3(45, 2), DMv, 0, stream>>>(We0, be0, We, W2, bias2);
  wcat_k<<<dim3(1152, 2), DMv, 0, stream>>>(Wl, Wr, Wres, WcatT);
  bas8_k<<<(Ecnt+255)/256, 256, 0, stream>>>(edge_attr, bas8, ofs, Ecnt);
  count_k<<<(Ecnt+255)/256, 256, 0, stream>>>(tgts, cnt, Ecnt);
  int nblk = (Nn + 255)/256;
  scan1_k<<<nblk, 256, 0, stream>>>(cnt, rowptr, bsum, Nn);
  scan2_k<<<1, 256, 0, stream>>>(bsum, bsumx, nblk);
  scan3_k<<<nblk, 256, 0, stream>>>(rowptr, bsumx, Nn, Ecnt);
  fill_k<<<(Ecnt+255)/256, 256, 0, stream>>>(tgts, rowptr, fillA, eidxA, Ecnt);
  loop_eproj_k<<<(Nn+3)/4, 256, 0, stream>>>(edge_attr, rowptr, eidxA, W2, eproj_loop, Nn);

  for (int l = 0; l < 2; ++l) {
    mfma_cat_k<<<dim3(9, (Nn+127)/128), 256, 0, stream>>>(
        hbf, WcatT + (size_t)l*1152*DMv,
        bl_ + (size_t)l*DMv, br_ + (size_t)l*DMv, bias_g + (size_t)l*DMv,
        xlB, xrB, hresB, Nn);
    fused_gat2_k<<<(Nn+7)/8, 256, 0, stream>>>(
        xlB, xrB, hresB, bas8, ofs, rowptr, eidxA, srcs,
        W2 + (size_t)l*44*DMv, bias2 + (size_t)l*DMv,
        eproj_loop + (size_t)l*Nn*DMv,
        att + (size_t)l*DMv, ln_g + (size_t)l*DMv, ln_b + (size_t)l*DMv,
        hbf, Nn);
  }
  bn_reduce_k<<<200, DMv, 0, stream>>>(hbf, bnsum, Nn);
  bn_params_k<<<1, DMv, 0, stream>>>(bnsum, bn_g, bn_b, scsh, Nn);
  bn_apply_k<<<Nn, DMv, 0, stream>>>(hbf, scsh, (float*)d_out);
}